// Round 1
// 87.984 us; speedup vs baseline: 1.0626x; 1.0626x over previous
//
#include <hip/hip_runtime.h>

// v7: cooperative LDS fragment generation (1.0x exp redundancy).
// v6 generated A/B fragments privately per wave: quads {0,1} duplicate gy,
// {0,2} duplicate gx -> 167M lane-exps (2x unique) and ~96 VALU + 32 exp per
// lane per K-step vs 4 MFMAs. v7: per 32-atom chunk all 8 waves cooperatively
// write gy[32][128] + gx[32][128] f16 into LDS (wave = one axis x 8-atom
// group; atom params are wave-uniform broadcasts), then each wave ds_read_b128s
// its 4 fragments (layout: lane = row + 32*(k>>3), elem = k&7 -- same as v6).
// 16 exps/lane/chunk (was 64). Stride 40 f16 = 80 B: 8 consecutive positions
// cover all 32 banks -> conflict-free b128. Double-buffered, 1 barrier/chunk.
// red[] aliases the staging buffers (union) to keep LDS at 64 KB -> 2 blocks/CU.

#define S 128
#define NS 32            // K-splits: 31 x 640 + 1 x 160 atoms
#define PER 640
#define BLOCK 512        // 8 waves: quad = wav&3, half (K-half of chunk) = wav>>2
#define KC 32            // atoms per chunk (2 MFMA K-steps)
#define GSTR 40          // f16 per position row: 32 atoms + 8 pad (80 B)

typedef _Float16 f16;
typedef _Float16 f16x2 __attribute__((ext_vector_type(2)));
typedef _Float16 f16x8 __attribute__((ext_vector_type(8)));
typedef float floatx16 __attribute__((ext_vector_type(16)));

#if __has_builtin(__builtin_amdgcn_exp2f)
#define FAST_EXP2(x) __builtin_amdgcn_exp2f(x)
#else
#define FAST_EXP2(x) exp2f(x)
#endif
#if __has_builtin(__builtin_amdgcn_rcpf)
#define FAST_RCP(x) __builtin_amdgcn_rcpf(x)
#else
#define FAST_RCP(x) (1.0f / (x))
#endif

static __device__ __forceinline__ f16x2 PKRTZ(float a, float b) {
#if __has_builtin(__builtin_amdgcn_cvt_pkrtz)
    return __builtin_bit_cast(f16x2, __builtin_amdgcn_cvt_pkrtz(a, b));
#else
    return (f16x2){(f16)a, (f16)b};
#endif
}

union frag_u { f16x8 v; f16x2 h[4]; };

union SharedU {
    struct {
        float4 sG[2][PER];           // per-axis params (mu, z, w, pad): 20480 B
        f16 g[2][2][S * GSTR];       // [buf][axis][pos*GSTR + atom]: 40960 B
    } m;
    float red[4 * 4096];             // 64 KB cross-half reduce (post-loop alias)
};

__global__ __launch_bounds__(BLOCK, 4) void k_proj(
    const float* __restrict__ mol,   // (B, A, 3)
    const float* __restrict__ stds,  // (A)
    const float* __restrict__ dens,  // (A)
    f16* __restrict__ part,          // (B*NS, 128*128) f16 partials, frag order
    int B, int A)
{
    __shared__ SharedU sh;

    const int ks   = blockIdx.x;
    const int b    = blockIdx.y;
    const int tid  = threadIdx.x;
    const int lane = tid & 63;
    const int wav  = tid >> 6;
    const int quad = wav & 3;        // image quadrant (64x64)
    const int half = wav >> 2;       // K-half within chunk (16 atoms)
    const int l31  = lane & 31;
    const int hi   = lane >> 5;

    const int a0  = ks * PER;
    const int a1  = min(a0 + PER, A);
    const int cnt = a1 - a0;          // 640 or 160, both divisible by KC

    for (int i = tid; i < cnt; i += BLOCK) {
        const int a = a0 + i;
        const size_t idx = (size_t)b * A + a;
        float x  = mol[idx * 3 + 0];
        float y  = mol[idx * 3 + 1];
        float v  = stds[a] * stds[a];
        float rv = FAST_RCP(v);
        float z  = -0.72134752044448f * rv;                 // -0.5*log2(e)/var
        float w  = __log2f(dens[a] * 0.15915494309189535f * rv);
        sh.m.sG[0][i] = make_float4(x, z, 0.f, 0.f);        // gx: no coef
        sh.m.sG[1][i] = make_float4(y, z, w,   0.f);        // gy: carries coef
    }
    __syncthreads();

    const int nc = cnt >> 5;          // chunks of 32 atoms: 20 or 5

    // generation role: wave -> (axis, 8-atom group); positions = lane, lane+64
    const int gaxis = wav >> 2;       // 0 = gx (cols), 1 = gy (rows)
    const int agrp  = wav & 3;
    const float c0  = (float)lane - 63.5f;

    // compute role addresses (f16 units)
    const int arow = (quad >> 1) * 64 + l31;
    const int acol = (quad & 1) * 64 + l31;
    const int aoff = half * 16 + hi * 8;   // k = chunk-atom: elem j -> aoff+j

    floatx16 acc[2][2];
#pragma unroll
    for (int rr = 0; rr < 2; ++rr)
#pragma unroll
        for (int cb = 0; cb < 2; ++cb) acc[rr][cb] = (floatx16){0.f};

    auto GEN = [&](int c, int buf) {
        const float4* prm = &sh.m.sG[gaxis][c * KC + agrp * 8];  // wave-uniform
        f16* dst = &sh.m.g[buf][gaxis][lane * GSTR + agrp * 8];
        frag_u V0, V1;
#pragma unroll
        for (int i2 = 0; i2 < 4; ++i2) {
            float e0[2], e1[2];
#pragma unroll
            for (int u = 0; u < 2; ++u) {
                float4 p = prm[i2 * 2 + u];      // (mu, z, w)
                float d  = c0 - p.x;
                float t  = p.y * d;
                float g0 = fmaf(t, d, p.z);
                float g1 = fmaf(128.0f, t, fmaf(4096.0f, p.y, g0));  // pos +64
                e0[u] = FAST_EXP2(g0);
                e1[u] = FAST_EXP2(g1);
            }
            V0.h[i2] = PKRTZ(e0[0], e0[1]);
            V1.h[i2] = PKRTZ(e1[0], e1[1]);
        }
        *(f16x8*)dst                = V0.v;      // pos = lane
        *(f16x8*)(dst + 64 * GSTR)  = V1.v;      // pos = lane + 64
    };

    GEN(0, 0);
    __syncthreads();

    for (int c = 0; c < nc; ++c) {
        const int cb = c & 1;
        const f16* gy = sh.m.g[cb][1];
        const f16* gx = sh.m.g[cb][0];
        frag_u A0, A1, B0, B1;
        A0.v = *(const f16x8*)(gy + arow * GSTR + aoff);
        A1.v = *(const f16x8*)(gy + (arow + 32) * GSTR + aoff);
        B0.v = *(const f16x8*)(gx + acol * GSTR + aoff);
        B1.v = *(const f16x8*)(gx + (acol + 32) * GSTR + aoff);
        acc[0][0] = __builtin_amdgcn_mfma_f32_32x32x16_f16(A0.v, B0.v, acc[0][0], 0, 0, 0);
        acc[0][1] = __builtin_amdgcn_mfma_f32_32x32x16_f16(A0.v, B1.v, acc[0][1], 0, 0, 0);
        acc[1][0] = __builtin_amdgcn_mfma_f32_32x32x16_f16(A1.v, B0.v, acc[1][0], 0, 0, 0);
        acc[1][1] = __builtin_amdgcn_mfma_f32_32x32x16_f16(A1.v, B1.v, acc[1][1], 0, 0, 0);
        if (c + 1 < nc) GEN(c + 1, cb ^ 1);      // fills other buffer
        __syncthreads();
    }

    // cross-half reduce: [j][lane] layout (lane-consecutive -> conflict-free)
    float* rq = sh.red + quad * 4096;
    if (half == 0) {
#pragma unroll
        for (int rr = 0; rr < 2; ++rr)
#pragma unroll
            for (int cb = 0; cb < 2; ++cb) {
                float* t = rq + (rr * 2 + cb) * 1024 + lane;
#pragma unroll
                for (int j = 0; j < 16; ++j) t[j * 64] = acc[rr][cb][j];
            }
    }
    __syncthreads();

    if (half == 1) {
        f16* base = part + ((size_t)(b * NS + ks)) * (S * S) + lane * 16;
#pragma unroll
        for (int rr = 0; rr < 2; ++rr)
#pragma unroll
            for (int cb = 0; cb < 2; ++cb) {
                float* t = rq + (rr * 2 + cb) * 1024 + lane;
                floatx16 v = acc[rr][cb];
#pragma unroll
                for (int j = 0; j < 16; ++j) v[j] += t[j * 64];
                const int tileidx = ((quad >> 1) * 2 + rr) * 4 + ((quad & 1) * 2 + cb);
                f16* pq = base + (size_t)tileidx * 1024;
                frag_u lo, hiv;
#pragma unroll
                for (int jp = 0; jp < 4; ++jp) {
                    lo.h[jp]  = PKRTZ(v[2 * jp],     v[2 * jp + 1]);
                    hiv.h[jp] = PKRTZ(v[2 * jp + 8], v[2 * jp + 9]);
                }
                *(f16x8*)(pq + 0) = lo.v;
                *(f16x8*)(pq + 8) = hiv.v;
            }
    }
}

// sum NS f16 partials per batch. v7: 4 waves/block each sum 8 slices (512
// blocks -> 2/CU, was 128 blocks = half the CUs idle); LDS combine; un-permute.
__global__ __launch_bounds__(256) void k_reduce(const f16* __restrict__ part,
                                                float* __restrict__ out) {
    __shared__ float lred[3][64][9];   // +1 pad: conflict-free strided stores
    const int b    = blockIdx.z;
    const int lane = threadIdx.x & 63;
    const int w    = threadIdx.x >> 6;
    const int f8   = (blockIdx.x * 64 + lane) * 8;   // frag-order base idx

    const f16* src = part + (size_t)b * NS * (S * S) + (size_t)(w * 8) * (S * S) + f8;
    float s[8] = {0.f};
#pragma unroll
    for (int t = 0; t < 8; ++t) {
        f16x8 v = *(const f16x8*)&src[(size_t)t * (S * S)];
#pragma unroll
        for (int i = 0; i < 8; ++i) s[i] += (float)v[i];
    }

    if (w) {
#pragma unroll
        for (int i = 0; i < 8; ++i) lred[w - 1][lane][i] = s[i];
    }
    __syncthreads();

    if (w == 0) {
#pragma unroll
        for (int j = 0; j < 3; ++j)
#pragma unroll
            for (int i = 0; i < 8; ++i) s[i] += lred[j][lane][i];

        // decode f8 = tile*1024 + lane_f*16 + reg0; tile = r*4 + c (32x32 tiles)
        const int reg0   = f8 & 15;
        const int lane_f = (f8 >> 4) & 63;
        const int tile   = f8 >> 10;
        const int r      = tile >> 2;
        const int cc     = tile & 3;
        // mfma_32x32 C/D: col = lane&31, row = (reg&3) + 8*(reg>>2) + 4*(lane>>5)
        const int rowb = r * 32 + 4 * (lane_f >> 5);
        const int col  = cc * 32 + (lane_f & 31);
#pragma unroll
        for (int i = 0; i < 8; ++i) {
            const int reg = reg0 + i;
            const int row = rowb + (reg & 3) + 8 * (reg >> 2);
            out[((size_t)b * S + row) * S + col] = s[i];
        }
    }
}

extern "C" void kernel_launch(void* const* d_in, const int* in_sizes, int n_in,
                              void* d_out, int out_size, void* d_ws, size_t ws_size,
                              hipStream_t stream) {
    const float* mol  = (const float*)d_in[0];
    const float* stds = (const float*)d_in[1];
    const float* dens = (const float*)d_in[2];
    float* out = (float*)d_out;

    const int A = in_sizes[1];             // 20000
    const int B = in_sizes[0] / (A * 3);   // 16

    f16* part = (f16*)d_ws;                // B*NS*16384*2 = 16.8 MB

    k_proj<<<dim3(NS, B), dim3(BLOCK), 0, stream>>>(mol, stds, dens, part, B, A);
    k_reduce<<<dim3((S * S) / (64 * 8), 1, B), dim3(256), 0, stream>>>(part, out);
}